// Round 1
// baseline (352.099 us; speedup 1.0000x reference)
//
#include <hip/hip_runtime.h>
#include <hip/hip_bf16.h>
#include <math.h>

// (B,S,D,H) = (2,2048,1024,16), DK=64
#define B_ 2
#define S_ 2048
#define D_ 1024
#define H_ 16
#define DK_ 64

#define ROPE_C 0.4152410118609203f   // log2(10000)/32
#define LOG2E 1.4426950408889634f

typedef float f4 __attribute__((ext_vector_type(4)));
typedef short s8 __attribute__((ext_vector_type(8)));

__device__ __forceinline__ ushort f2b(float f) {
  union { float f; uint u; } v; v.f = f;
  uint u = v.u + 0x7fffu + ((v.u >> 16) & 1u);
  return (ushort)(u >> 16);
}

__device__ __forceinline__ float b2f(ushort u) {
  union { uint u; float f; } v; v.u = ((uint)u) << 16;
  return v.f;
}

// async global->LDS DMA, 16 B per lane. LDS dest = wave-uniform base + lane*16.
__device__ __forceinline__ void async16(const ushort* g, ushort* l) {
  __builtin_amdgcn_global_load_lds(
      (const __attribute__((address_space(1))) uint*)g,
      (__attribute__((address_space(3))) uint*)l, 16, 0, 0);
}

// ---------------------------------------------------------------------------
// Prep 1: fp32 -> bf16 flat convert (4M elems). 8 elems/thread.
// ---------------------------------------------------------------------------
__global__ __launch_bounds__(256) void conv_x(const float* __restrict__ in,
                                              ushort* __restrict__ out) {
  int idx = (blockIdx.x * 256 + threadIdx.x) * 8;
  float4 a = *(const float4*)&in[idx];
  float4 b = *(const float4*)&in[idx + 4];
  ushort tmp[8] = {f2b(a.x), f2b(a.y), f2b(a.z), f2b(a.w),
                   f2b(b.x), f2b(b.y), f2b(b.z), f2b(b.w)};
  *(uint4*)&out[idx] = *(uint4*)tmp;
}

// ---------------------------------------------------------------------------
// Prep 2: W fp32 [K=1024][N=1024] -> Wt bf16 [N][K]. 64x64 LDS tiles.
// ---------------------------------------------------------------------------
__global__ __launch_bounds__(256) void transpose_w(const float* __restrict__ W,
                                                   ushort* __restrict__ Wt) {
  __shared__ ushort T[64][65];
  const int t = threadIdx.x;
  const int k0 = blockIdx.x * 64, n0 = blockIdx.y * 64;
  #pragma unroll
  for (int i = 0; i < 16; ++i) {
    int e = t + i * 256, r = e >> 6, c = e & 63;
    T[c][r] = f2b(W[(size_t)(k0 + r) * D_ + n0 + c]);
  }
  __syncthreads();
  #pragma unroll
  for (int i = 0; i < 16; ++i) {
    int e = t + i * 256, r = e >> 6, c = e & 63;
    Wt[(size_t)(n0 + r) * D_ + k0 + c] = T[r][c];
  }
}

// ---------------------------------------------------------------------------
// MFMA GEMM, m97-style K-loop: BM=BN=128, BK=32, 4 waves 2x2, 4x4 frags/wave.
// Staging: global_load_lds width-16, unpadded [128][32] LDS, XOR-block swizzle.
// MODE 0: PLAIN epilogue -> dense bf16 [4096][1024] per matrix (bias only).
// MODE 2: fp32 [M][N] + bias (final projection), direct stores.
// ---------------------------------------------------------------------------
template <int MODE>
__global__ __launch_bounds__(256) void gemm_mfma(
    const ushort* __restrict__ A0, const ushort* __restrict__ A1,
    const ushort* __restrict__ A2, const ushort* __restrict__ Bt,
    const float* __restrict__ bb0, const float* __restrict__ bb1,
    const float* __restrict__ bb2,
    ushort* __restrict__ oq, ushort* __restrict__ ok, ushort* __restrict__ ov,
    float* __restrict__ oo) {
  __shared__ ushort As[128 * 32];
  __shared__ ushort Bs[128 * 32];
  __shared__ ushort Es[(MODE == 0) ? 9216 : 1];  // [64][144] epilogue scratch

  const int t = threadIdx.x, w = t >> 6, l = t & 63;
  const int m0 = blockIdx.x * 128, n0 = blockIdx.y * 128;
  const int wm = (w >> 1) * 64, wn = (w & 1) * 64;
  const int lm = l & 15, h8 = (l >> 4) * 8, q4 = (l >> 4) * 4;
  const int hb = l >> 4;

  const ushort* A;
  const float* bias;
  int mat = 0;
  if constexpr (MODE == 0) {
    mat = n0 >> 10;
    A = (mat == 0) ? A0 : (mat == 1) ? A1 : A2;
    bias = (mat == 0) ? bb0 : (mat == 1) ? bb1 : bb2;
  } else {
    A = A0; bias = bb0;
  }

  const int srow = w * 32 + (l >> 2);
  const int pb = l & 3;
  const int lb = pb ^ (srow & 3);
  const ushort* gA = A + (size_t)(m0 + srow) * D_ + lb * 8;
  const ushort* gB = Bt + (size_t)(n0 + srow) * D_ + lb * 8;
  ushort* lA = As + w * 1024;
  ushort* lB = Bs + w * 1024;

  f4 acc[4][4];
  #pragma unroll
  for (int i = 0; i < 4; ++i)
    #pragma unroll
    for (int j = 0; j < 4; ++j) acc[i][j] = (f4){0.f, 0.f, 0.f, 0.f};

  for (int k0 = 0; k0 < D_; k0 += 32) {
    async16(gA + k0, lA);
    async16(gA + 16 * D_ + k0, lA + 512);
    async16(gB + k0, lB);
    async16(gB + 16 * D_ + k0, lB + 512);
    __syncthreads();
    s8 af[4], bfr[4];
    #pragma unroll
    for (int mt = 0; mt < 4; ++mt) {
      int ra = wm + mt * 16 + lm;
      af[mt] = *(const s8*)&As[ra * 32 + ((hb ^ (ra & 3)) << 3)];
    }
    #pragma unroll
    for (int nt = 0; nt < 4; ++nt) {
      int rb = wn + nt * 16 + lm;
      bfr[nt] = *(const s8*)&Bs[rb * 32 + ((hb ^ (rb & 3)) << 3)];
    }
    #pragma unroll
    for (int mt = 0; mt < 4; ++mt)
      #pragma unroll
      for (int nt = 0; nt < 4; ++nt)
        acc[mt][nt] = __builtin_amdgcn_mfma_f32_16x16x32_bf16(af[mt], bfr[nt], acc[mt][nt], 0, 0, 0);
    __syncthreads();
  }

  // ---- epilogue ----
  if constexpr (MODE == 2) {
    #pragma unroll
    for (int nt = 0; nt < 4; ++nt) {
      int n = n0 + wn + nt * 16 + lm;
      float bv = bias[n];
      #pragma unroll
      for (int mt = 0; mt < 4; ++mt)
        #pragma unroll
        for (int r = 0; r < 4; ++r)
          oo[(size_t)(m0 + wm + mt * 16 + q4 + r) * D_ + n] = acc[mt][nt][r] + bv;
    }
  } else {
    ushort* dst = (mat == 0) ? oq : (mat == 1) ? ok : ov;
    const int nm0 = n0 & 1023;
    #pragma unroll
    for (int p = 0; p < 2; ++p) {
      if ((w >> 1) == p) {
        #pragma unroll
        for (int nt = 0; nt < 4; ++nt) {
          int col = wn + nt * 16 + lm;
          float bv = bias[nm0 + col];
          #pragma unroll
          for (int mt = 0; mt < 4; ++mt)
            #pragma unroll
            for (int r = 0; r < 4; ++r)
              Es[(mt * 16 + q4 + r) * 144 + col] = f2b(acc[mt][nt][r] + bv);
        }
      }
      __syncthreads();
      #pragma unroll
      for (int i = 0; i < 4; ++i) {
        int e = t + i * 256, row = e >> 4, ch = e & 15;
        *(uint4*)&dst[(size_t)(m0 + p * 64 + row) * D_ + nm0 + ch * 8] =
            *(const uint4*)&Es[row * 144 + ch * 8];
      }
      __syncthreads();
    }
  }
}

// ---------------------------------------------------------------------------
// RoPE + relayout pass (memory-bound). Grid (32 bh, 32 s-tiles), 256 thr.
// Q is pre-scaled by (1/sqrt(DK)) * LOG2E so attention works in exp2 domain.
// ---------------------------------------------------------------------------
__global__ __launch_bounds__(256) void rope_pass(
    const ushort* __restrict__ qtmp, const ushort* __restrict__ ktmp,
    const ushort* __restrict__ vtmp,
    ushort* __restrict__ qfb, ushort* __restrict__ kfb,
    ushort* __restrict__ vtb) {
  __shared__ ushort T[64][72];
  const int t = threadIdx.x;
  const int bh = blockIdx.x, st = blockIdx.y;
  const int b = bh >> 4, h = bh & 15;
  const int s0 = st * 64;
  const int r = t >> 2, c0 = (t & 3) * 16;
  const int s = s0 + r;

  float cs[16], sn[16];
  const float pos = (float)s;
  #pragma unroll
  for (int j = 0; j < 16; ++j) {
    float invf = exp2f(-(float)((c0 + j) & 31) * ROPE_C);
    __sincosf(pos * invf, &sn[j], &cs[j]);
  }

  const size_t src = ((size_t)(b * S_ + s)) * D_ + h * 64 + c0;
  const size_t dstqk = ((size_t)bh * S_ + s) * DK_ + c0;

  #pragma unroll
  for (int tensor = 0; tensor < 2; ++tensor) {
    const ushort* in = tensor ? ktmp : qtmp;
    ushort* out = tensor ? kfb : qfb;
    const float scale = tensor ? 1.f : 0.18033688011112042f;  // 0.125*LOG2E
    uint4 raw0 = *(const uint4*)&in[src];
    uint4 raw1 = *(const uint4*)&in[src + 8];
    ushort xr[16];
    *(uint4*)&xr[0] = raw0;
    *(uint4*)&xr[8] = raw1;
    float x[16];
    #pragma unroll
    for (int j = 0; j < 16; ++j) x[j] = b2f(xr[j]);
    ushort o[16];
    #pragma unroll
    for (int j = 0; j < 16; j += 2) {
      float e = x[j] * cs[j] - x[j + 1] * sn[j + 1];
      float d = x[j] * sn[j] + x[j + 1] * cs[j + 1];
      o[j] = f2b(e * scale);
      o[j + 1] = f2b(d * scale);
    }
    *(uint4*)&out[dstqk] = *(const uint4*)&o[0];
    *(uint4*)&out[dstqk + 8] = *(const uint4*)&o[8];
  }

  {
    uint4 raw0 = *(const uint4*)&vtmp[src];
    uint4 raw1 = *(const uint4*)&vtmp[src + 8];
    ushort xr[16];
    *(uint4*)&xr[0] = raw0;
    *(uint4*)&xr[8] = raw1;
    #pragma unroll
    for (int j = 0; j < 16; ++j) T[c0 + j][r] = xr[j];
    __syncthreads();
    const size_t dstv = ((size_t)bh * DK_ + r) * S_ + s0 + c0;
    *(uint4*)&vtb[dstv] = *(const uint4*)&T[r][c0];
    *(uint4*)&vtb[dstv + 8] = *(const uint4*)&T[r][c0 + 8];
  }
}

// ---------------------------------------------------------------------------
// MFMA flash attention v2: barrier-free K-loop.
//  - K/V/Q fragments loaded DIRECTLY global->VGPR (K reads are fully
//    coalesced 2KB spans; V^T reads are 16x64B, L2-resident). No K/V LDS,
//    no __syncthreads in the K-loop. Only P round-trips through LDS
//    (same-wave rows -> lgkmcnt only).
//  - Grid (32 bh, 32 qt), longest-tile-first (qt = 31-by) for LPT balance.
//    1024 blocks -> 4 blocks/CU, 16 waves/CU (vs 8 before).
//  - exp2-domain scores (LOG2E folded into Q pre-scale), tree reductions,
//    defer-max (THR=4) skips alpha-shuffles + O-rescale on stable tiles.
// ---------------------------------------------------------------------------
__global__ __launch_bounds__(256, 4) void attn_mfma(const ushort* __restrict__ qf,
                                                    const ushort* __restrict__ kf,
                                                    const ushort* __restrict__ vtf,
                                                    ushort* __restrict__ ctx) {
  __shared__ ushort Ps[64][72];

  const int t = threadIdx.x, w = t >> 6, l = t & 63;
  const int bh = blockIdx.x, qt = 31 - (int)blockIdx.y;
  const int i0 = qt * 64;
  const int lm = l & 15, h8 = (l >> 4) * 8, q4 = (l >> 4) * 4, w16 = w * 16;
  const size_t base = (size_t)bh * S_ * DK_;
  const int b = bh >> 4, h = bh & 15;

  // Q fragment: loop-invariant per wave (B-frag, col = q-row w16+lm)
  const ushort* qp = qf + base + (size_t)(i0 + w16 + lm) * DK_ + h8;
  const s8 bq0 = *(const s8*)qp;
  const s8 bq1 = *(const s8*)(qp + 32);

  const ushort* kb = kf + base + (size_t)lm * DK_ + h8;   // + (j0+nt*16)*DK_
  const ushort* vb = vtf + base + (size_t)lm * S_ + h8;   // + nt*16*S_ + j0

  f4 O[4];
  #pragma unroll
  for (int i = 0; i < 4; ++i) O[i] = (f4){0.f, 0.f, 0.f, 0.f};
  float m_ = -1e30f, l_ = 0.f;  // softmax state for q-row w16+lm (exp2 domain)

  for (int jt = 0; jt <= qt; ++jt) {
    const int j0 = jt * 64;

    // ---- S^T = K @ Q^T : direct global K-frags (coalesced 2KB/instr) ----
    f4 st[4];
    __builtin_amdgcn_s_setprio(1);
    #pragma unroll
    for (int nt = 0; nt < 4; ++nt) {
      const ushort* kr = kb + (size_t)(j0 + nt * 16) * DK_;
      s8 a0 = *(const s8*)kr;
      s8 a1 = *(const s8*)(kr + 32);
      f4 a = (f4){0.f, 0.f, 0.f, 0.f};
      a = __builtin_amdgcn_mfma_f32_16x16x32_bf16(a0, bq0, a, 0, 0, 0);
      a = __builtin_amdgcn_mfma_f32_16x16x32_bf16(a1, bq1, a, 0, 0, 0);
      st[nt] = a;
    }
    __builtin_amdgcn_s_setprio(0);

    // ---- prefetch V^T frags (latency hides under softmax) ----
    s8 vv0[4], vv1[4];
    #pragma unroll
    for (int nt = 0; nt < 4; ++nt) {
      const ushort* vr = vb + (size_t)(nt * 16) * S_ + j0;
      vv0[nt] = *(const s8*)vr;
      vv1[nt] = *(const s8*)(vr + 32);
    }

    if (jt == qt) {  // causal: key nt*16+q4+r vs qrow w16+lm
      #pragma unroll
      for (int nt = 0; nt < 4; ++nt)
        #pragma unroll
        for (int r = 0; r < 4; ++r)
          if (nt * 16 + q4 + r > w16 + lm) st[nt][r] = -1e30f;
    }

    // ---- row max: tree (depth 4) + 2 shfl ----
    float x0 = fmaxf(fmaxf(st[0][0], st[0][1]), fmaxf(st[0][2], st[0][3]));
    float x1 = fmaxf(fmaxf(st[1][0], st[1][1]), fmaxf(st[1][2], st[1][3]));
    float x2 = fmaxf(fmaxf(st[2][0], st[2][1]), fmaxf(st[2][2], st[2][3]));
    float x3 = fmaxf(fmaxf(st[3][0], st[3][1]), fmaxf(st[3][2], st[3][3]));
    float pm = fmaxf(fmaxf(x0, x1), fmaxf(x2, x3));
    pm = fmaxf(pm, __shfl_xor(pm, 16));
    pm = fmaxf(pm, __shfl_xor(pm, 32));

    // ---- defer-max (T13): skip rescale when max didn't grow past THR ----
    const bool stable = __all(pm <= m_ + 4.0f);
    float mn = m_, alpha = 1.f;
    if (!stable) {
      mn = fmaxf(m_, pm);
      alpha = exp2f(m_ - mn);
      m_ = mn;
    }

    // ---- exp (exp2 domain) + row sum: tree + 2 shfl ----
    #pragma unroll
    for (int nt = 0; nt < 4; ++nt)
      #pragma unroll
      for (int r = 0; r < 4; ++r)
        st[nt][r] = exp2f(st[nt][r] - mn);
    float s0 = (st[0][0] + st[0][1]) + (st[0][2] + st[0][3]);
    float s1 = (st[1][0] + st[1][1]) + (st[1][2] + st[1][3]);
    float s2 = (st[2][0] + st[2][1]) + (st[2][2] + st[2][3]);
    float s3 = (st[3][0] + st[3][1]) + (st[3][2] + st[3][3]);
    float ps = (s0 + s1) + (s2 + s3);
    ps += __shfl_xor(ps, 16);
    ps += __shfl_xor(ps, 32);

    if (stable) {
      l_ += ps;
    } else {
      l_ = l_ * alpha + ps;
      float ar[4];
      #pragma unroll
      for (int r = 0; r < 4; ++r) ar[r] = __shfl(alpha, q4 + r);
      #pragma unroll
      for (int nt = 0; nt < 4; ++nt)
        #pragma unroll
        for (int r = 0; r < 4; ++r) O[nt][r] *= ar[r];
    }

    // ---- P -> LDS (same-wave rows; lgkmcnt-ordered, no barrier) ----
    #pragma unroll
    for (int nt = 0; nt < 4; ++nt) {
      ushort pk[4] = {f2b(st[nt][0]), f2b(st[nt][1]), f2b(st[nt][2]), f2b(st[nt][3])};
      *(uint2*)&Ps[w16 + lm][nt * 16 + q4] = *(const uint2*)pk;
    }
    s8 ap0 = *(const s8*)&Ps[w16 + lm][h8];
    s8 ap1 = *(const s8*)&Ps[w16 + lm][h8 + 32];

    // ---- PV ----
    __builtin_amdgcn_s_setprio(1);
    #pragma unroll
    for (int nt = 0; nt < 4; ++nt) {
      O[nt] = __builtin_amdgcn_mfma_f32_16x16x32_bf16(ap0, vv0[nt], O[nt], 0, 0, 0);
      O[nt] = __builtin_amdgcn_mfma_f32_16x16x32_bf16(ap1, vv1[nt], O[nt], 0, 0, 0);
    }
    __builtin_amdgcn_s_setprio(0);
  }

  // ---- epilogue: 1/l via shfl, transpose-stage in Ps, coalesced stores ----
  float il[4];
  #pragma unroll
  for (int r = 0; r < 4; ++r) il[r] = 1.f / __shfl(l_, q4 + r);
  #pragma unroll
  for (int nt = 0; nt < 4; ++nt)
    #pragma unroll
    for (int r = 0; r < 4; ++r)
      Ps[w16 + q4 + r][nt * 16 + lm] = f2b(O[nt][r] * il[r]);
  __syncthreads();
  #pragma unroll
  for (int i = 0; i < 2; ++i) {
    int e = t + i * 256, row = e >> 3, ch = e & 7;
    int s = i0 + row;
    *(uint4*)&ctx[((size_t)(b * S_ + s)) * D_ + h * 64 + ch * 8] =
        *(const uint4*)&Ps[row][ch * 8];
  }
}

// ---------------------------------------------------------------------------
extern "C" void kernel_launch(void* const* d_in, const int* in_sizes, int n_in,
                              void* d_out, int out_size, void* d_ws, size_t ws_size,
                              hipStream_t stream) {
  const float* q_in = (const float*)d_in[0];
  const float* k_in = (const float*)d_in[1];
  const float* v_in = (const float*)d_in[2];
  const float* Wq = (const float*)d_in[3];
  const float* bq = (const float*)d_in[4];
  const float* Wk = (const float*)d_in[5];
  const float* bk = (const float*)d_in[6];
  const float* Wv = (const float*)d_in[7];
  const float* bv = (const float*)d_in[8];
  const float* Wo = (const float*)d_in[9];
  const float* bo = (const float*)d_in[10];

  const size_t NE = (size_t)B_ * S_ * D_;  // 4,194,304
  ushort* Xbq = (ushort*)d_ws;
  ushort* Xbk = Xbq + NE;
  ushort* Xbv = Xbk + NE;
  ushort* Wtqkv = Xbv + NE;              // [3072][1024] bf16
  ushort* Wto = Wtqkv + 3 * 1024 * 1024;
  ushort* qtmp = Wto + 1024 * 1024;      // dense [4096][1024] bf16
  ushort* ktmp = qtmp + NE;
  ushort* vtmp = ktmp + NE;
  ushort* qfb = vtmp + NE;               // [bh][s][dk]
  ushort* kfb = qfb + NE;
  ushort* vtb = kfb + NE;                // [bh][dk][s]
  ushort* ctxb = qtmp;                   // alias: qtmp dead after rope_pass

  conv_x<<<2048, 256, 0, stream>>>(q_in, Xbq);
  conv_x<<<2048, 256, 0, stream>>>(k_in, Xbk);
  conv_x<<<2048, 256, 0, stream>>>(v_in, Xbv);
  transpose_w<<<dim3(16, 16), 256, 0, stream>>>(Wq, Wtqkv);
  transpose_w<<<dim3(16, 16), 256, 0, stream>>>(Wk, Wtqkv + 1024 * 1024);
  transpose_w<<<dim3(16, 16), 256, 0, stream>>>(Wv, Wtqkv + 2 * 1024 * 1024);
  transpose_w<<<dim3(16, 16), 256, 0, stream>>>(Wo, Wto);

  gemm_mfma<0><<<dim3(32, 24), 256, 0, stream>>>(
      Xbq, Xbk, Xbv, Wtqkv, bq, bk, bv, qtmp, ktmp, vtmp, nullptr);

  rope_pass<<<dim3(32, 32), 256, 0, stream>>>(qtmp, ktmp, vtmp, qfb, kfb, vtb);

  attn_mfma<<<dim3(32, 32), 256, 0, stream>>>(qfb, kfb, vtb, ctxb);

  gemm_mfma<2><<<dim3(32, 8), 256, 0, stream>>>(
      ctxb, ctxb, ctxb, Wto, bo, bo, bo, nullptr, nullptr, nullptr,
      (float*)d_out);
}

// Round 2
// 257.671 us; speedup vs baseline: 1.3665x; 1.3665x over previous
//
#include <hip/hip_runtime.h>
#include <hip/hip_bf16.h>
#include <math.h>

// (B,S,D,H) = (2,2048,1024,16), DK=64
#define B_ 2
#define S_ 2048
#define D_ 1024
#define H_ 16
#define DK_ 64

#define ROPE_C 0.4152410118609203f   // log2(10000)/32
#define LOG2E 1.4426950408889634f

typedef float f4 __attribute__((ext_vector_type(4)));
typedef short s8 __attribute__((ext_vector_type(8)));

__device__ __forceinline__ ushort f2b(float f) {
  union { float f; uint u; } v; v.f = f;
  uint u = v.u + 0x7fffu + ((v.u >> 16) & 1u);
  return (ushort)(u >> 16);
}

__device__ __forceinline__ float b2f(ushort u) {
  union { uint u; float f; } v; v.u = ((uint)u) << 16;
  return v.f;
}

// async global->LDS DMA, 16 B per lane. LDS dest = wave-uniform base + lane*16.
__device__ __forceinline__ void async16(const ushort* g, ushort* l) {
  __builtin_amdgcn_global_load_lds(
      (const __attribute__((address_space(1))) uint*)g,
      (__attribute__((address_space(3))) uint*)l, 16, 0, 0);
}

// ---------------------------------------------------------------------------
// Prep 1: fp32 -> bf16 flat convert (4M elems). 8 elems/thread.
// ---------------------------------------------------------------------------
__global__ __launch_bounds__(256) void conv_x(const float* __restrict__ in,
                                              ushort* __restrict__ out) {
  int idx = (blockIdx.x * 256 + threadIdx.x) * 8;
  float4 a = *(const float4*)&in[idx];
  float4 b = *(const float4*)&in[idx + 4];
  ushort tmp[8] = {f2b(a.x), f2b(a.y), f2b(a.z), f2b(a.w),
                   f2b(b.x), f2b(b.y), f2b(b.z), f2b(b.w)};
  *(uint4*)&out[idx] = *(uint4*)tmp;
}

// ---------------------------------------------------------------------------
// Prep 2: W fp32 [K=1024][N=1024] -> Wt bf16 [N][K]. 64x64 LDS tiles.
// ---------------------------------------------------------------------------
__global__ __launch_bounds__(256) void transpose_w(const float* __restrict__ W,
                                                   ushort* __restrict__ Wt) {
  __shared__ ushort T[64][65];
  const int t = threadIdx.x;
  const int k0 = blockIdx.x * 64, n0 = blockIdx.y * 64;
  #pragma unroll
  for (int i = 0; i < 16; ++i) {
    int e = t + i * 256, r = e >> 6, c = e & 63;
    T[c][r] = f2b(W[(size_t)(k0 + r) * D_ + n0 + c]);
  }
  __syncthreads();
  #pragma unroll
  for (int i = 0; i < 16; ++i) {
    int e = t + i * 256, r = e >> 6, c = e & 63;
    Wt[(size_t)(n0 + r) * D_ + k0 + c] = T[r][c];
  }
}

// ---------------------------------------------------------------------------
// MFMA GEMM, m97-style K-loop: BM=BN=128, BK=32, 4 waves 2x2, 4x4 frags/wave.
// Staging: global_load_lds width-16, unpadded [128][32] LDS, XOR-block swizzle.
// MODE 0: PLAIN epilogue -> dense bf16 [4096][1024] per matrix (bias only).
// MODE 2: fp32 [M][N] + bias (final projection), direct stores.
// ---------------------------------------------------------------------------
template <int MODE>
__global__ __launch_bounds__(256) void gemm_mfma(
    const ushort* __restrict__ A0, const ushort* __restrict__ A1,
    const ushort* __restrict__ A2, const ushort* __restrict__ Bt,
    const float* __restrict__ bb0, const float* __restrict__ bb1,
    const float* __restrict__ bb2,
    ushort* __restrict__ oq, ushort* __restrict__ ok, ushort* __restrict__ ov,
    float* __restrict__ oo) {
  __shared__ ushort As[128 * 32];
  __shared__ ushort Bs[128 * 32];
  __shared__ ushort Es[(MODE == 0) ? 9216 : 1];  // [64][144] epilogue scratch

  const int t = threadIdx.x, w = t >> 6, l = t & 63;
  const int m0 = blockIdx.x * 128, n0 = blockIdx.y * 128;
  const int wm = (w >> 1) * 64, wn = (w & 1) * 64;
  const int lm = l & 15, h8 = (l >> 4) * 8, q4 = (l >> 4) * 4;
  const int hb = l >> 4;

  const ushort* A;
  const float* bias;
  int mat = 0;
  if constexpr (MODE == 0) {
    mat = n0 >> 10;
    A = (mat == 0) ? A0 : (mat == 1) ? A1 : A2;
    bias = (mat == 0) ? bb0 : (mat == 1) ? bb1 : bb2;
  } else {
    A = A0; bias = bb0;
  }

  const int srow = w * 32 + (l >> 2);
  const int pb = l & 3;
  const int lb = pb ^ (srow & 3);
  const ushort* gA = A + (size_t)(m0 + srow) * D_ + lb * 8;
  const ushort* gB = Bt + (size_t)(n0 + srow) * D_ + lb * 8;
  ushort* lA = As + w * 1024;
  ushort* lB = Bs + w * 1024;

  f4 acc[4][4];
  #pragma unroll
  for (int i = 0; i < 4; ++i)
    #pragma unroll
    for (int j = 0; j < 4; ++j) acc[i][j] = (f4){0.f, 0.f, 0.f, 0.f};

  for (int k0 = 0; k0 < D_; k0 += 32) {
    async16(gA + k0, lA);
    async16(gA + 16 * D_ + k0, lA + 512);
    async16(gB + k0, lB);
    async16(gB + 16 * D_ + k0, lB + 512);
    __syncthreads();
    s8 af[4], bfr[4];
    #pragma unroll
    for (int mt = 0; mt < 4; ++mt) {
      int ra = wm + mt * 16 + lm;
      af[mt] = *(const s8*)&As[ra * 32 + ((hb ^ (ra & 3)) << 3)];
    }
    #pragma unroll
    for (int nt = 0; nt < 4; ++nt) {
      int rb = wn + nt * 16 + lm;
      bfr[nt] = *(const s8*)&Bs[rb * 32 + ((hb ^ (rb & 3)) << 3)];
    }
    #pragma unroll
    for (int mt = 0; mt < 4; ++mt)
      #pragma unroll
      for (int nt = 0; nt < 4; ++nt)
        acc[mt][nt] = __builtin_amdgcn_mfma_f32_16x16x32_bf16(af[mt], bfr[nt], acc[mt][nt], 0, 0, 0);
    __syncthreads();
  }

  // ---- epilogue ----
  if constexpr (MODE == 2) {
    #pragma unroll
    for (int nt = 0; nt < 4; ++nt) {
      int n = n0 + wn + nt * 16 + lm;
      float bv = bias[n];
      #pragma unroll
      for (int mt = 0; mt < 4; ++mt)
        #pragma unroll
        for (int r = 0; r < 4; ++r)
          oo[(size_t)(m0 + wm + mt * 16 + q4 + r) * D_ + n] = acc[mt][nt][r] + bv;
    }
  } else {
    ushort* dst = (mat == 0) ? oq : (mat == 1) ? ok : ov;
    const int nm0 = n0 & 1023;
    #pragma unroll
    for (int p = 0; p < 2; ++p) {
      if ((w >> 1) == p) {
        #pragma unroll
        for (int nt = 0; nt < 4; ++nt) {
          int col = wn + nt * 16 + lm;
          float bv = bias[nm0 + col];
          #pragma unroll
          for (int mt = 0; mt < 4; ++mt)
            #pragma unroll
            for (int r = 0; r < 4; ++r)
              Es[(mt * 16 + q4 + r) * 144 + col] = f2b(acc[mt][nt][r] + bv);
        }
      }
      __syncthreads();
      #pragma unroll
      for (int i = 0; i < 4; ++i) {
        int e = t + i * 256, row = e >> 4, ch = e & 15;
        *(uint4*)&dst[(size_t)(m0 + p * 64 + row) * D_ + nm0 + ch * 8] =
            *(const uint4*)&Es[row * 144 + ch * 8];
      }
      __syncthreads();
    }
  }
}

// ---------------------------------------------------------------------------
// RoPE + relayout pass (memory-bound). Grid (32 bh, 32 s-tiles), 256 thr.
// Q is pre-scaled by (1/sqrt(DK)) * LOG2E so attention works in exp2 domain.
// ---------------------------------------------------------------------------
__global__ __launch_bounds__(256) void rope_pass(
    const ushort* __restrict__ qtmp, const ushort* __restrict__ ktmp,
    const ushort* __restrict__ vtmp,
    ushort* __restrict__ qfb, ushort* __restrict__ kfb,
    ushort* __restrict__ vtb) {
  __shared__ ushort T[64][72];
  const int t = threadIdx.x;
  const int bh = blockIdx.x, st = blockIdx.y;
  const int b = bh >> 4, h = bh & 15;
  const int s0 = st * 64;
  const int r = t >> 2, c0 = (t & 3) * 16;
  const int s = s0 + r;

  float cs[16], sn[16];
  const float pos = (float)s;
  #pragma unroll
  for (int j = 0; j < 16; ++j) {
    float invf = exp2f(-(float)((c0 + j) & 31) * ROPE_C);
    __sincosf(pos * invf, &sn[j], &cs[j]);
  }

  const size_t src = ((size_t)(b * S_ + s)) * D_ + h * 64 + c0;
  const size_t dstqk = ((size_t)bh * S_ + s) * DK_ + c0;

  #pragma unroll
  for (int tensor = 0; tensor < 2; ++tensor) {
    const ushort* in = tensor ? ktmp : qtmp;
    ushort* out = tensor ? kfb : qfb;
    const float scale = tensor ? 1.f : 0.18033688011112042f;  // 0.125*LOG2E
    uint4 raw0 = *(const uint4*)&in[src];
    uint4 raw1 = *(const uint4*)&in[src + 8];
    ushort xr[16];
    *(uint4*)&xr[0] = raw0;
    *(uint4*)&xr[8] = raw1;
    float x[16];
    #pragma unroll
    for (int j = 0; j < 16; ++j) x[j] = b2f(xr[j]);
    ushort o[16];
    #pragma unroll
    for (int j = 0; j < 16; j += 2) {
      float e = x[j] * cs[j] - x[j + 1] * sn[j + 1];
      float d = x[j] * sn[j] + x[j + 1] * cs[j + 1];
      o[j] = f2b(e * scale);
      o[j + 1] = f2b(d * scale);
    }
    *(uint4*)&out[dstqk] = *(const uint4*)&o[0];
    *(uint4*)&out[dstqk + 8] = *(const uint4*)&o[8];
  }

  {
    uint4 raw0 = *(const uint4*)&vtmp[src];
    uint4 raw1 = *(const uint4*)&vtmp[src + 8];
    ushort xr[16];
    *(uint4*)&xr[0] = raw0;
    *(uint4*)&xr[8] = raw1;
    #pragma unroll
    for (int j = 0; j < 16; ++j) T[c0 + j][r] = xr[j];
    __syncthreads();
    const size_t dstv = ((size_t)bh * DK_ + r) * S_ + s0 + c0;
    *(uint4*)&vtb[dstv] = *(const uint4*)&T[r][c0];
    *(uint4*)&vtb[dstv + 8] = *(const uint4*)&T[r][c0 + 8];
  }
}

// ---------------------------------------------------------------------------
// MFMA flash attention v3: shared LDS K/V staging (1x traffic, 4-wave reuse)
// + one-tile-deep double buffer via global_load_lds: DMA for tile jt+1 is
// issued at the TOP of iter jt; the single end-of-iter barrier's vmcnt drain
// lands after the full compute phase has hidden the DMA latency.
//  - unpadded [64][64] K/V tiles, XOR-block swizzle with PRE-SWIZZLED global
//    source (global_load_lds writes linearly; rule: both-sides-or-neither).
//  - Q in registers (loop-invariant), P->LDS round-trip same-wave (no bar).
//  - Grid (32 bh, 32 qt) longest-first (LPT): 1024 blocks, 3 blocks/CU
//    (LDS 41 KB), 12 waves/CU.
//  - exp2-domain scores, tree reductions, defer-max (THR=4), setprio MFMA.
// ---------------------------------------------------------------------------
__global__ __launch_bounds__(256, 3) void attn_mfma(const ushort* __restrict__ qf,
                                                    const ushort* __restrict__ kf,
                                                    const ushort* __restrict__ vtf,
                                                    ushort* __restrict__ ctx) {
  __shared__ ushort Ks[2][4096];   // [buf][64 rows][64] keys x dk, swizzled
  __shared__ ushort Vs[2][4096];   // [buf][64 rows][64] dk x keys, swizzled
  __shared__ ushort Ps[64][72];

  const int t = threadIdx.x, w = t >> 6, l = t & 63;
  const int bh = blockIdx.x, qt = 31 - (int)blockIdx.y;
  const int i0 = qt * 64;
  const int lm = l & 15, hb = l >> 4, h8 = hb * 8, q4 = hb * 4, w16 = w * 16;
  const size_t base = (size_t)bh * S_ * DK_;
  const int b = bh >> 4, h = bh & 15;

  // ---- staging geometry: one async16 covers 8 rows (8 lanes/row x 16B) ----
  const int sr = l >> 3, pbk = l & 7;
  const int rA = w * 16 + sr, rB = rA + 8;           // rA&7 == rB&7 == sr
  const int swS = (pbk ^ sr) << 3;                    // pre-swizzled src block
  const ushort* gkA = kf + base + (size_t)rA * DK_ + swS;
  const ushort* gkB = kf + base + (size_t)rB * DK_ + swS;
  const ushort* gvA = vtf + base + (size_t)rA * S_ + swS;
  const ushort* gvB = vtf + base + (size_t)rB * S_ + swS;

#define STAGE(bf, j0)                                       \
  {                                                         \
    ushort* lk = &Ks[bf][w * 1024];                         \
    ushort* lv = &Vs[bf][w * 1024];                         \
    async16(gkA + (size_t)(j0) * DK_, lk);                  \
    async16(gkB + (size_t)(j0) * DK_, lk + 512);            \
    async16(gvA + (j0), lv);                                \
    async16(gvB + (j0), lv + 512);                          \
  }

  // ---- Q fragment: loop-invariant per wave (B-frag, col = q-row w16+lm) ----
  const ushort* qp = qf + base + (size_t)(i0 + w16 + lm) * DK_ + h8;
  const s8 bq0 = *(const s8*)qp;
  const s8 bq1 = *(const s8*)(qp + 32);

  // ---- read-side swizzle constants (row rr = nt*16+lm -> rr&7 = lm&7) ----
  const int swr = lm & 7;
  const int cA = (hb ^ swr) << 3;         // global block hb   (cols h8..h8+7)
  const int cB = ((hb + 4) ^ swr) << 3;   // global block hb+4 (cols 32+h8..)

  STAGE(0, 0);

  f4 O[4];
  #pragma unroll
  for (int i = 0; i < 4; ++i) O[i] = (f4){0.f, 0.f, 0.f, 0.f};
  float m_ = -1e30f, l_ = 0.f;  // softmax state for q-row w16+lm (exp2 domain)

  __syncthreads();

  for (int jt = 0; jt <= qt; ++jt) {
    const int cur = jt & 1;
    if (jt < qt) STAGE(cur ^ 1, (jt + 1) * 64);   // prefetch next tile
    const ushort* Kb = Ks[cur];
    const ushort* Vb = Vs[cur];

    // ---- S^T = K @ Q^T ----
    f4 st[4];
    __builtin_amdgcn_s_setprio(1);
    #pragma unroll
    for (int nt = 0; nt < 4; ++nt) {
      const ushort* kRow = Kb + (nt * 16 + lm) * 64;
      s8 a0 = *(const s8*)&kRow[cA];
      s8 a1 = *(const s8*)&kRow[cB];
      f4 a = (f4){0.f, 0.f, 0.f, 0.f};
      a = __builtin_amdgcn_mfma_f32_16x16x32_bf16(a0, bq0, a, 0, 0, 0);
      a = __builtin_amdgcn_mfma_f32_16x16x32_bf16(a1, bq1, a, 0, 0, 0);
      st[nt] = a;
    }
    __builtin_amdgcn_s_setprio(0);

    if (jt == qt) {  // causal: key nt*16+q4+r vs qrow w16+lm
      #pragma unroll
      for (int nt = 0; nt < 4; ++nt)
        #pragma unroll
        for (int r = 0; r < 4; ++r)
          if (nt * 16 + q4 + r > w16 + lm) st[nt][r] = -1e30f;
    }

    // ---- row max: tree (depth 4) + 2 shfl ----
    float x0 = fmaxf(fmaxf(st[0][0], st[0][1]), fmaxf(st[0][2], st[0][3]));
    float x1 = fmaxf(fmaxf(st[1][0], st[1][1]), fmaxf(st[1][2], st[1][3]));
    float x2 = fmaxf(fmaxf(st[2][0], st[2][1]), fmaxf(st[2][2], st[2][3]));
    float x3 = fmaxf(fmaxf(st[3][0], st[3][1]), fmaxf(st[3][2], st[3][3]));
    float pm = fmaxf(fmaxf(x0, x1), fmaxf(x2, x3));
    pm = fmaxf(pm, __shfl_xor(pm, 16));
    pm = fmaxf(pm, __shfl_xor(pm, 32));

    // ---- defer-max (T13): skip rescale when max didn't grow past THR ----
    const bool stable = __all(pm <= m_ + 4.0f);
    float mn = m_, alpha = 1.f;
    if (!stable) {
      mn = fmaxf(m_, pm);
      alpha = exp2f(m_ - mn);
      m_ = mn;
    }

    // ---- exp (exp2 domain) + row sum: tree + 2 shfl ----
    #pragma unroll
    for (int nt = 0; nt < 4; ++nt)
      #pragma unroll
      for (int r = 0; r < 4; ++r)
        st[nt][r] = exp2f(st[nt][r] - mn);
    float s0 = (st[0][0] + st[0][1]) + (st[0][2] + st[0][3]);
    float s1 = (st[1][0] + st[1][1]) + (st[1][2] + st[1][3]);
    float s2 = (st[2][0] + st[2][1]) + (st[2][2] + st[2][3]);
    float s3 = (st[3][0] + st[3][1]) + (st[3][2] + st[3][3]);
    float ps = (s0 + s1) + (s2 + s3);
    ps += __shfl_xor(ps, 16);
    ps += __shfl_xor(ps, 32);

    if (stable) {
      l_ += ps;
    } else {
      l_ = l_ * alpha + ps;
      float ar[4];
      #pragma unroll
      for (int r = 0; r < 4; ++r) ar[r] = __shfl(alpha, q4 + r);
      #pragma unroll
      for (int nt = 0; nt < 4; ++nt)
        #pragma unroll
        for (int r = 0; r < 4; ++r) O[nt][r] *= ar[r];
    }

    // ---- P -> LDS (same-wave rows; lgkmcnt-ordered, no barrier) ----
    #pragma unroll
    for (int nt = 0; nt < 4; ++nt) {
      ushort pk[4] = {f2b(st[nt][0]), f2b(st[nt][1]), f2b(st[nt][2]), f2b(st[nt][3])};
      *(uint2*)&Ps[w16 + lm][nt * 16 + q4] = *(const uint2*)pk;
    }
    s8 ap0 = *(const s8*)&Ps[w16 + lm][h8];
    s8 ap1 = *(const s8*)&Ps[w16 + lm][h8 + 32];

    // ---- PV ----
    __builtin_amdgcn_s_setprio(1);
    #pragma unroll
    for (int nt = 0; nt < 4; ++nt) {
      const ushort* vRow = Vb + (nt * 16 + lm) * 64;
      s8 v0 = *(const s8*)&vRow[cA];
      s8 v1 = *(const s8*)&vRow[cB];
      O[nt] = __builtin_amdgcn_mfma_f32_16x16x32_bf16(ap0, v0, O[nt], 0, 0, 0);
      O[nt] = __builtin_amdgcn_mfma_f32_16x16x32_bf16(ap1, v1, O[nt], 0, 0, 0);
    }
    __builtin_amdgcn_s_setprio(0);

    // single barrier: (a) makes prefetched tile visible (vmcnt drain had the
    // whole compute phase to land), (b) protects buf reuse one iter later.
    __syncthreads();
  }

  // ---- epilogue: 1/l via shfl, transpose-stage in Ps, coalesced stores ----
  float il[4];
  #pragma unroll
  for (int r = 0; r < 4; ++r) il[r] = 1.f / __shfl(l_, q4 + r);
  #pragma unroll
  for (int nt = 0; nt < 4; ++nt)
    #pragma unroll
    for (int r = 0; r < 4; ++r)
      Ps[w16 + q4 + r][nt * 16 + lm] = f2b(O[nt][r] * il[r]);
  __syncthreads();
  #pragma unroll
  for (int i = 0; i < 2; ++i) {
    int e = t + i * 256, row = e >> 3, ch = e & 7;
    int s = i0 + row;
    *(uint4*)&ctx[((size_t)(b * S_ + s)) * D_ + h * 64 + ch * 8] =
        *(const uint4*)&Ps[row][ch * 8];
  }
#undef STAGE
}

// ---------------------------------------------------------------------------
extern "C" void kernel_launch(void* const* d_in, const int* in_sizes, int n_in,
                              void* d_out, int out_size, void* d_ws, size_t ws_size,
                              hipStream_t stream) {
  const float* q_in = (const float*)d_in[0];
  const float* k_in = (const float*)d_in[1];
  const float* v_in = (const float*)d_in[2];
  const float* Wq = (const float*)d_in[3];
  const float* bq = (const float*)d_in[4];
  const float* Wk = (const float*)d_in[5];
  const float* bk = (const float*)d_in[6];
  const float* Wv = (const float*)d_in[7];
  const float* bv = (const float*)d_in[8];
  const float* Wo = (const float*)d_in[9];
  const float* bo = (const float*)d_in[10];

  const size_t NE = (size_t)B_ * S_ * D_;  // 4,194,304
  ushort* Xbq = (ushort*)d_ws;
  ushort* Xbk = Xbq + NE;
  ushort* Xbv = Xbk + NE;
  ushort* Wtqkv = Xbv + NE;              // [3072][1024] bf16
  ushort* Wto = Wtqkv + 3 * 1024 * 1024;
  ushort* qtmp = Wto + 1024 * 1024;      // dense [4096][1024] bf16
  ushort* ktmp = qtmp + NE;
  ushort* vtmp = ktmp + NE;
  ushort* qfb = vtmp + NE;               // [bh][s][dk]
  ushort* kfb = qfb + NE;
  ushort* vtb = kfb + NE;                // [bh][dk][s]
  ushort* ctxb = qtmp;                   // alias: qtmp dead after rope_pass

  conv_x<<<2048, 256, 0, stream>>>(q_in, Xbq);
  conv_x<<<2048, 256, 0, stream>>>(k_in, Xbk);
  conv_x<<<2048, 256, 0, stream>>>(v_in, Xbv);
  transpose_w<<<dim3(16, 16), 256, 0, stream>>>(Wq, Wtqkv);
  transpose_w<<<dim3(16, 16), 256, 0, stream>>>(Wk, Wtqkv + 1024 * 1024);
  transpose_w<<<dim3(16, 16), 256, 0, stream>>>(Wv, Wtqkv + 2 * 1024 * 1024);
  transpose_w<<<dim3(16, 16), 256, 0, stream>>>(Wo, Wto);

  gemm_mfma<0><<<dim3(32, 24), 256, 0, stream>>>(
      Xbq, Xbk, Xbv, Wtqkv, bq, bk, bv, qtmp, ktmp, vtmp, nullptr);

  rope_pass<<<dim3(32, 32), 256, 0, stream>>>(qtmp, ktmp, vtmp, qfb, kfb, vtb);

  attn_mfma<<<dim3(32, 32), 256, 0, stream>>>(qfb, kfb, vtb, ctxb);

  gemm_mfma<2><<<dim3(32, 8), 256, 0, stream>>>(
      ctxb, ctxb, ctxb, Wto, bo, bo, bo, nullptr, nullptr, nullptr,
      (float*)d_out);
}

// Round 3
// 228.736 us; speedup vs baseline: 1.5393x; 1.1265x over previous
//
#include <hip/hip_runtime.h>
#include <hip/hip_bf16.h>
#include <math.h>

// (B,S,D,H) = (2,2048,1024,16), DK=64
#define B_ 2
#define S_ 2048
#define D_ 1024
#define H_ 16
#define DK_ 64

#define ROPE_C 0.4152410118609203f   // log2(10000)/32
#define LOG2E 1.4426950408889634f

typedef float f4 __attribute__((ext_vector_type(4)));
typedef short s8 __attribute__((ext_vector_type(8)));

__device__ __forceinline__ ushort f2b(float f) {
  union { float f; uint u; } v; v.f = f;
  uint u = v.u + 0x7fffu + ((v.u >> 16) & 1u);
  return (ushort)(u >> 16);
}

__device__ __forceinline__ float b2f(ushort u) {
  union { uint u; float f; } v; v.u = ((uint)u) << 16;
  return v.f;
}

// packed f32x2 -> bf16x2 (T12: no builtin on gfx950; lo = src0)
__device__ __forceinline__ uint cvtpk(float a, float b) {
  uint r;
  asm("v_cvt_pk_bf16_f32 %0, %1, %2" : "=v"(r) : "v"(a), "v"(b));
  return r;
}

// async global->LDS DMA, 16 B per lane. LDS dest = wave-uniform base + lane*16.
__device__ __forceinline__ void async16(const ushort* g, ushort* l) {
  __builtin_amdgcn_global_load_lds(
      (const __attribute__((address_space(1))) uint*)g,
      (__attribute__((address_space(3))) uint*)l, 16, 0, 0);
}

// ---------------------------------------------------------------------------
// Fused prep: blocks 0..6143 = fp32->bf16 convert of q/k/v (8 elems/thread);
// blocks 6144..7167 = W transpose (4 matrices, 16x16 tiles of 64x64).
// One launch instead of 7.
// ---------------------------------------------------------------------------
__global__ __launch_bounds__(256) void prep_all(
    const float* __restrict__ q_in, const float* __restrict__ k_in,
    const float* __restrict__ v_in,
    ushort* __restrict__ Xbq, ushort* __restrict__ Xbk, ushort* __restrict__ Xbv,
    const float* __restrict__ Wq, const float* __restrict__ Wk,
    const float* __restrict__ Wv, const float* __restrict__ Wo,
    ushort* __restrict__ Wtqkv, ushort* __restrict__ Wto) {
  __shared__ ushort T[64][65];
  const int bid = blockIdx.x, t = threadIdx.x;
  if (bid < 6144) {
    const int m = bid >> 11;  // /2048
    const float* in = (m == 0) ? q_in : (m == 1) ? k_in : v_in;
    ushort* out = (m == 0) ? Xbq : (m == 1) ? Xbk : Xbv;
    int idx = ((bid & 2047) * 256 + t) * 8;
    float4 a = *(const float4*)&in[idx];
    float4 b = *(const float4*)&in[idx + 4];
    ushort tmp[8] = {f2b(a.x), f2b(a.y), f2b(a.z), f2b(a.w),
                     f2b(b.x), f2b(b.y), f2b(b.z), f2b(b.w)};
    *(uint4*)&out[idx] = *(uint4*)tmp;
  } else {
    const int tb = bid - 6144;
    const int m = tb >> 8;
    const float* W = (m == 0) ? Wq : (m == 1) ? Wk : (m == 2) ? Wv : Wo;
    ushort* Wt = (m == 3) ? Wto : Wtqkv + (size_t)m * 1024 * 1024;
    const int k0 = (tb & 15) * 64, n0 = ((tb >> 4) & 15) * 64;
    #pragma unroll
    for (int i = 0; i < 16; ++i) {
      int e = t + i * 256, r = e >> 6, c = e & 63;
      T[c][r] = f2b(W[(size_t)(k0 + r) * D_ + n0 + c]);
    }
    __syncthreads();
    #pragma unroll
    for (int i = 0; i < 16; ++i) {
      int e = t + i * 256, r = e >> 6, c = e & 63;
      Wt[(size_t)(n0 + r) * D_ + k0 + c] = T[r][c];
    }
  }
}

// ---------------------------------------------------------------------------
// MFMA GEMM v2: BM=BN=128, BK=32, 4 waves 2x2, 4x4 frags/wave.
// Double-buffered global_load_lds staging: prefetch K-step k0+32 at the TOP
// of step k0, ONE barrier per step (vmcnt drain hidden under compute).
// LDS carved from one 32 KB block; MODE 0's Es epilogue scratch aliases it
// (K-loop buffers dead after the final barrier).
// MODE 0: dense bf16 [4096][1024] per matrix (bias only).
// MODE 2: fp32 [M][N] + bias (final projection), direct stores.
// ---------------------------------------------------------------------------
template <int MODE>
__global__ __launch_bounds__(256) void gemm_mfma(
    const ushort* __restrict__ A0, const ushort* __restrict__ A1,
    const ushort* __restrict__ A2, const ushort* __restrict__ Bt,
    const float* __restrict__ bb0, const float* __restrict__ bb1,
    const float* __restrict__ bb2,
    ushort* __restrict__ oq, ushort* __restrict__ ok, ushort* __restrict__ ov,
    float* __restrict__ oo) {
  __shared__ ushort SM[16384];  // 32 KB: As[2][4096] | Bs[2][4096]
  ushort* Es = SM;              // MODE 0 epilogue [64][144]=9216, aliases K-loop bufs

  const int t = threadIdx.x, w = t >> 6, l = t & 63;
  const int m0 = blockIdx.x * 128, n0 = blockIdx.y * 128;
  const int wm = (w >> 1) * 64, wn = (w & 1) * 64;
  const int lm = l & 15, q4 = (l >> 4) * 4;
  const int hb = l >> 4;

  const ushort* A;
  const float* bias;
  int mat = 0;
  if constexpr (MODE == 0) {
    mat = n0 >> 10;
    A = (mat == 0) ? A0 : (mat == 1) ? A1 : A2;
    bias = (mat == 0) ? bb0 : (mat == 1) ? bb1 : bb2;
  } else {
    A = A0; bias = bb0;
  }

  const int srow = w * 32 + (l >> 2);
  const int pb = l & 3;
  const int lb = pb ^ (srow & 3);
  const ushort* gA = A + (size_t)(m0 + srow) * D_ + lb * 8;
  const ushort* gB = Bt + (size_t)(n0 + srow) * D_ + lb * 8;

#define GSTAGE(bf, kk)                                   \
  {                                                      \
    ushort* lA = SM + (bf) * 4096 + w * 1024;            \
    ushort* lB = SM + 8192 + (bf) * 4096 + w * 1024;     \
    async16(gA + (kk), lA);                              \
    async16(gA + 16 * D_ + (kk), lA + 512);              \
    async16(gB + (kk), lB);                              \
    async16(gB + 16 * D_ + (kk), lB + 512);              \
  }

  f4 acc[4][4];
  #pragma unroll
  for (int i = 0; i < 4; ++i)
    #pragma unroll
    for (int j = 0; j < 4; ++j) acc[i][j] = (f4){0.f, 0.f, 0.f, 0.f};

  GSTAGE(0, 0);
  __syncthreads();

  for (int k0 = 0; k0 < D_; k0 += 32) {
    const int bf = (k0 >> 5) & 1;
    if (k0 + 32 < D_) GSTAGE(bf ^ 1, k0 + 32);
    const ushort* Asb = SM + bf * 4096;
    const ushort* Bsb = SM + 8192 + bf * 4096;
    s8 af[4], bfr[4];
    #pragma unroll
    for (int mt = 0; mt < 4; ++mt) {
      int ra = wm + mt * 16 + lm;
      af[mt] = *(const s8*)&Asb[ra * 32 + ((hb ^ (ra & 3)) << 3)];
    }
    #pragma unroll
    for (int nt = 0; nt < 4; ++nt) {
      int rb = wn + nt * 16 + lm;
      bfr[nt] = *(const s8*)&Bsb[rb * 32 + ((hb ^ (rb & 3)) << 3)];
    }
    __builtin_amdgcn_s_setprio(1);
    #pragma unroll
    for (int mt = 0; mt < 4; ++mt)
      #pragma unroll
      for (int nt = 0; nt < 4; ++nt)
        acc[mt][nt] = __builtin_amdgcn_mfma_f32_16x16x32_bf16(af[mt], bfr[nt], acc[mt][nt], 0, 0, 0);
    __builtin_amdgcn_s_setprio(0);
    // one barrier: releases buf for restage next iter + makes prefetch visible
    __syncthreads();
  }

  // ---- epilogue ----
  if constexpr (MODE == 2) {
    #pragma unroll
    for (int nt = 0; nt < 4; ++nt) {
      int n = n0 + wn + nt * 16 + lm;
      float bv = bias[n];
      #pragma unroll
      for (int mt = 0; mt < 4; ++mt)
        #pragma unroll
        for (int r = 0; r < 4; ++r)
          oo[(size_t)(m0 + wm + mt * 16 + q4 + r) * D_ + n] = acc[mt][nt][r] + bv;
    }
  } else {
    ushort* dst = (mat == 0) ? oq : (mat == 1) ? ok : ov;
    const int nm0 = n0 & 1023;
    #pragma unroll
    for (int p = 0; p < 2; ++p) {
      if ((w >> 1) == p) {
        #pragma unroll
        for (int nt = 0; nt < 4; ++nt) {
          int col = wn + nt * 16 + lm;
          float bv = bias[nm0 + col];
          #pragma unroll
          for (int mt = 0; mt < 4; ++mt)
            #pragma unroll
            for (int r = 0; r < 4; ++r)
              Es[(mt * 16 + q4 + r) * 144 + col] = f2b(acc[mt][nt][r] + bv);
        }
      }
      __syncthreads();
      #pragma unroll
      for (int i = 0; i < 4; ++i) {
        int e = t + i * 256, row = e >> 4, ch = e & 15;
        *(uint4*)&dst[(size_t)(m0 + p * 64 + row) * D_ + nm0 + ch * 8] =
            *(const uint4*)&Es[row * 144 + ch * 8];
      }
      __syncthreads();
    }
  }
#undef GSTAGE
}

// ---------------------------------------------------------------------------
// RoPE + relayout pass (memory-bound). Grid (32 bh, 32 s-tiles), 256 thr.
// Q is pre-scaled by (1/sqrt(DK)) * LOG2E so attention works in exp2 domain.
// ---------------------------------------------------------------------------
__global__ __launch_bounds__(256) void rope_pass(
    const ushort* __restrict__ qtmp, const ushort* __restrict__ ktmp,
    const ushort* __restrict__ vtmp,
    ushort* __restrict__ qfb, ushort* __restrict__ kfb,
    ushort* __restrict__ vtb) {
  __shared__ ushort T[64][72];
  const int t = threadIdx.x;
  const int bh = blockIdx.x, st = blockIdx.y;
  const int b = bh >> 4, h = bh & 15;
  const int s0 = st * 64;
  const int r = t >> 2, c0 = (t & 3) * 16;
  const int s = s0 + r;

  float cs[16], sn[16];
  const float pos = (float)s;
  #pragma unroll
  for (int j = 0; j < 16; ++j) {
    float invf = exp2f(-(float)((c0 + j) & 31) * ROPE_C);
    __sincosf(pos * invf, &sn[j], &cs[j]);
  }

  const size_t src = ((size_t)(b * S_ + s)) * D_ + h * 64 + c0;
  const size_t dstqk = ((size_t)bh * S_ + s) * DK_ + c0;

  #pragma unroll
  for (int tensor = 0; tensor < 2; ++tensor) {
    const ushort* in = tensor ? ktmp : qtmp;
    ushort* out = tensor ? kfb : qfb;
    const float scale = tensor ? 1.f : 0.18033688011112042f;  // 0.125*LOG2E
    uint4 raw0 = *(const uint4*)&in[src];
    uint4 raw1 = *(const uint4*)&in[src + 8];
    ushort xr[16];
    *(uint4*)&xr[0] = raw0;
    *(uint4*)&xr[8] = raw1;
    float x[16];
    #pragma unroll
    for (int j = 0; j < 16; ++j) x[j] = b2f(xr[j]);
    ushort o[16];
    #pragma unroll
    for (int j = 0; j < 16; j += 2) {
      float e = x[j] * cs[j] - x[j + 1] * sn[j + 1];
      float d = x[j] * sn[j] + x[j + 1] * cs[j + 1];
      o[j] = f2b(e * scale);
      o[j + 1] = f2b(d * scale);
    }
    *(uint4*)&out[dstqk] = *(const uint4*)&o[0];
    *(uint4*)&out[dstqk + 8] = *(const uint4*)&o[8];
  }

  {
    uint4 raw0 = *(const uint4*)&vtmp[src];
    uint4 raw1 = *(const uint4*)&vtmp[src + 8];
    ushort xr[16];
    *(uint4*)&xr[0] = raw0;
    *(uint4*)&xr[8] = raw1;
    #pragma unroll
    for (int j = 0; j < 16; ++j) T[c0 + j][r] = xr[j];
    __syncthreads();
    const size_t dstv = ((size_t)bh * DK_ + r) * S_ + s0 + c0;
    *(uint4*)&vtb[dstv] = *(const uint4*)&T[r][c0];
    *(uint4*)&vtb[dstv + 8] = *(const uint4*)&T[r][c0 + 8];
  }
}

// ---------------------------------------------------------------------------
// MFMA flash attention v4:
//  - v3's prefetch + single-barrier LDS pipeline for K/V (kept).
//  - P pack via v_cvt_pk_bf16_f32 (8 instr vs ~56 VALU for hand f2b).
//  - Ps unpadded [64][64], XOR-8-block swizzle (same read constants cA/cB as
//    K/V) -> ~2-way (free) LDS access; LDS = 40960 B -> up to 4 blocks/CU.
//  - exp2-domain scores, tree reductions, defer-max (THR=4), setprio MFMA.
// ---------------------------------------------------------------------------
__global__ __launch_bounds__(256, 4) void attn_mfma(const ushort* __restrict__ qf,
                                                    const ushort* __restrict__ kf,
                                                    const ushort* __restrict__ vtf,
                                                    ushort* __restrict__ ctx) {
  __shared__ ushort Ks[2][4096];   // [buf][64 rows][64] keys x dk, swizzled
  __shared__ ushort Vs[2][4096];   // [buf][64 rows][64] dk x keys, swizzled
  __shared__ ushort PsS[4096];     // [64][64] XOR-swizzled P scratch

  const int t = threadIdx.x, w = t >> 6, l = t & 63;
  const int bh = blockIdx.x, qt = 31 - (int)blockIdx.y;
  const int i0 = qt * 64;
  const int lm = l & 15, hb = l >> 4, h8 = hb * 8, q4 = hb * 4, w16 = w * 16;
  const size_t base = (size_t)bh * S_ * DK_;
  const int b = bh >> 4, h = bh & 15;

  // ---- staging geometry: one async16 covers 8 rows (8 lanes/row x 16B) ----
  const int sr = l >> 3, pbk = l & 7;
  const int rA = w * 16 + sr, rB = rA + 8;           // rA&7 == rB&7 == sr
  const int swS = (pbk ^ sr) << 3;                    // pre-swizzled src block
  const ushort* gkA = kf + base + (size_t)rA * DK_ + swS;
  const ushort* gkB = kf + base + (size_t)rB * DK_ + swS;
  const ushort* gvA = vtf + base + (size_t)rA * S_ + swS;
  const ushort* gvB = vtf + base + (size_t)rB * S_ + swS;

#define STAGE(bf, j0)                                       \
  {                                                         \
    ushort* lk = &Ks[bf][w * 1024];                         \
    ushort* lv = &Vs[bf][w * 1024];                         \
    async16(gkA + (size_t)(j0) * DK_, lk);                  \
    async16(gkB + (size_t)(j0) * DK_, lk + 512);            \
    async16(gvA + (j0), lv);                                \
    async16(gvB + (j0), lv + 512);                          \
  }

  // ---- Q fragment: loop-invariant per wave (B-frag, col = q-row w16+lm) ----
  const ushort* qp = qf + base + (size_t)(i0 + w16 + lm) * DK_ + h8;
  const s8 bq0 = *(const s8*)qp;
  const s8 bq1 = *(const s8*)(qp + 32);

  // ---- read-side swizzle constants (row rr = nt*16+lm -> rr&7 = lm&7) ----
  const int swr = lm & 7;
  const int cA = (hb ^ swr) << 3;         // block hb   (cols h8..h8+7)
  const int cB = ((hb + 4) ^ swr) << 3;   // block hb+4 (cols 32+h8..)
  // P-write swizzled bases: col = nt*16+q4 -> blk8 = 2nt+(hb>>1), sub = (hb&1)*4
  const int prow = (w16 + lm) * 64;
  const int psub = ((hb & 1) << 2) + ((hb >> 1) ^ swr);  // careful: see below

  STAGE(0, 0);

  f4 O[4];
  #pragma unroll
  for (int i = 0; i < 4; ++i) O[i] = (f4){0.f, 0.f, 0.f, 0.f};
  float m_ = -1e30f, l_ = 0.f;  // softmax state for q-row w16+lm (exp2 domain)

  __syncthreads();

  for (int jt = 0; jt <= qt; ++jt) {
    const int cur = jt & 1;
    if (jt < qt) STAGE(cur ^ 1, (jt + 1) * 64);   // prefetch next tile
    const ushort* Kb = Ks[cur];
    const ushort* Vb = Vs[cur];

    // ---- S^T = K @ Q^T ----
    f4 st[4];
    __builtin_amdgcn_s_setprio(1);
    #pragma unroll
    for (int nt = 0; nt < 4; ++nt) {
      const ushort* kRow = Kb + (nt * 16 + lm) * 64;
      s8 a0 = *(const s8*)&kRow[cA];
      s8 a1 = *(const s8*)&kRow[cB];
      f4 a = (f4){0.f, 0.f, 0.f, 0.f};
      a = __builtin_amdgcn_mfma_f32_16x16x32_bf16(a0, bq0, a, 0, 0, 0);
      a = __builtin_amdgcn_mfma_f32_16x16x32_bf16(a1, bq1, a, 0, 0, 0);
      st[nt] = a;
    }
    __builtin_amdgcn_s_setprio(0);

    if (jt == qt) {  // causal: key nt*16+q4+r vs qrow w16+lm
      #pragma unroll
      for (int nt = 0; nt < 4; ++nt)
        #pragma unroll
        for (int r = 0; r < 4; ++r)
          if (nt * 16 + q4 + r > w16 + lm) st[nt][r] = -1e30f;
    }

    // ---- row max: tree (depth 4) + 2 shfl ----
    float x0 = fmaxf(fmaxf(st[0][0], st[0][1]), fmaxf(st[0][2], st[0][3]));
    float x1 = fmaxf(fmaxf(st[1][0], st[1][1]), fmaxf(st[1][2], st[1][3]));
    float x2 = fmaxf(fmaxf(st[2][0], st[2][1]), fmaxf(st[2][2], st[2][3]));
    float x3 = fmaxf(fmaxf(st[3][0], st[3][1]), fmaxf(st[3][2], st[3][3]));
    float pm = fmaxf(fmaxf(x0, x1), fmaxf(x2, x3));
    pm = fmaxf(pm, __shfl_xor(pm, 16));
    pm = fmaxf(pm, __shfl_xor(pm, 32));

    // ---- defer-max (T13): skip rescale when max didn't grow past THR ----
    const bool stable = __all(pm <= m_ + 4.0f);
    float mn = m_, alpha = 1.f;
    if (!stable) {
      mn = fmaxf(m_, pm);
      alpha = exp2f(m_ - mn);
      m_ = mn;
    }

    // ---- exp (exp2 domain) + row sum: tree + 2 shfl ----
    #pragma unroll
    for (int nt = 0; nt < 4; ++nt)
      #pragma unroll
      for (int r = 0; r < 4; ++r)
        st[nt][r] = exp2f(st[nt][r] - mn);
    float s0 = (st[0][0] + st[0][1]) + (st[0][2] + st[0][3]);
    float s1 = (st[1][0] + st[1][1]) + (st[1][2] + st[1][3]);
    float s2 = (st[2][0] + st[2][1]) + (st[2][2] + st[2][3]);
    float s3 = (st[3][0] + st[3][1]) + (st[3][2] + st[3][3]);
    float ps = (s0 + s1) + (s2 + s3);
    ps += __shfl_xor(ps, 16);
    ps += __shfl_xor(ps, 32);

    if (stable) {
      l_ += ps;
    } else {
      l_ = l_ * alpha + ps;
      float ar[4];
      #pragma unroll
      for (int r = 0; r < 4; ++r) ar[r] = __shfl(alpha, q4 + r);
      #pragma unroll
      for (int nt = 0; nt < 4; ++nt)
        #pragma unroll
        for (int r = 0; r < 4; ++r) O[nt][r] *= ar[r];
    }

    // ---- P -> LDS, packed via cvt_pk, swizzled (same-wave rows, no bar) ----
    #pragma unroll
    for (int nt = 0; nt < 4; ++nt) {
      uint2 pp;
      pp.x = cvtpk(st[nt][0], st[nt][1]);
      pp.y = cvtpk(st[nt][2], st[nt][3]);
      const int pidx = prow + ((((nt << 1) + (hb >> 1)) ^ swr) << 3) + ((hb & 1) << 2);
      *(uint2*)&PsS[pidx] = pp;
    }
    s8 ap0 = *(const s8*)&PsS[prow + cA];
    s8 ap1 = *(const s8*)&PsS[prow + cB];

    // ---- PV ----
    __builtin_amdgcn_s_setprio(1);
    #pragma unroll
    for (int nt = 0; nt < 4; ++nt) {
      const ushort* vRow = Vb + (nt * 16 + lm) * 64;
      s8 v0 = *(const s8*)&vRow[cA];
      s8 v1 = *(const s8*)&vRow[cB];
      O[nt] = __builtin_amdgcn_mfma_f32_16x16x32_bf16(ap0, v0, O[nt], 0, 0, 0);
      O[nt] = __builtin_amdgcn_mfma_f32_16x16x32_bf16(ap1, v1, O[nt], 0, 0, 0);
    }
    __builtin_amdgcn_s_setprio(0);

    // single barrier: prefetched tile visible + buf reuse protected.
    __syncthreads();
  }

  // ---- epilogue: 1/l via shfl, transpose-stage in PsS (swizzled), store ----
  float il[4];
  #pragma unroll
  for (int r = 0; r < 4; ++r) il[r] = 1.f / __shfl(l_, q4 + r);
  #pragma unroll
  for (int nt = 0; nt < 4; ++nt)
    #pragma unroll
    for (int r = 0; r < 4; ++r) {
      int row = w16 + q4 + r, col = nt * 16 + lm;
      PsS[row * 64 + ((((col >> 3) ^ (row & 7)) << 3)) + (col & 7)] =
          f2b(O[nt][r] * il[r]);
    }
  __syncthreads();
  #pragma unroll
  for (int i = 0; i < 2; ++i) {
    int e = t + i * 256, row = e >> 3, ch = e & 7;
    int s = i0 + row;
    *(uint4*)&ctx[((size_t)(b * S_ + s)) * D_ + h * 64 + ch * 8] =
        *(const uint4*)&PsS[row * 64 + ((ch ^ (row & 7)) << 3)];
  }
#undef STAGE
}

// ---------------------------------------------------------------------------
extern "C" void kernel_launch(void* const* d_in, const int* in_sizes, int n_in,
                              void* d_out, int out_size, void* d_ws, size_t ws_size,
                              hipStream_t stream) {
  const float* q_in = (const float*)d_in[0];
  const float* k_in = (const float*)d_in[1];
  const float* v_in = (const float*)d_in[2];
  const float* Wq = (const float*)d_in[3];
  const float* bq = (const float*)d_in[4];
  const float* Wk = (const float*)d_in[5];
  const float* bk = (const float*)d_in[6];
  const float* Wv = (const float*)d_in[7];
  const float* bv = (const float*)d_in[8];
  const float* Wo = (const float*)d_in[9];
  const float* bo = (const float*)d_in[10];

  const size_t NE = (size_t)B_ * S_ * D_;  // 4,194,304
  ushort* Xbq = (ushort*)d_ws;
  ushort* Xbk = Xbq + NE;
  ushort* Xbv = Xbk + NE;
  ushort* Wtqkv = Xbv + NE;              // [3072][1024] bf16
  ushort* Wto = Wtqkv + 3 * 1024 * 1024;
  ushort* qtmp = Wto + 1024 * 1024;      // dense [4096][1024] bf16
  ushort* ktmp = qtmp + NE;
  ushort* vtmp = ktmp + NE;
  ushort* qfb = vtmp + NE;               // [bh][s][dk]
  ushort* kfb = qfb + NE;
  ushort* vtb = kfb + NE;                // [bh][dk][s]
  ushort* ctxb = qtmp;                   // alias: qtmp dead after rope_pass

  prep_all<<<7168, 256, 0, stream>>>(q_in, k_in, v_in, Xbq, Xbk, Xbv,
                                     Wq, Wk, Wv, Wo, Wtqkv, Wto);

  gemm_mfma<0><<<dim3(32, 24), 256, 0, stream>>>(
      Xbq, Xbk, Xbv, Wtqkv, bq, bk, bv, qtmp, ktmp, vtmp, nullptr);

  rope_pass<<<dim3(32, 32), 256, 0, stream>>>(qtmp, ktmp, vtmp, qfb, kfb, vtb);

  attn_mfma<<<dim3(32, 32), 256, 0, stream>>>(qfb, kfb, vtb, ctxb);

  gemm_mfma<2><<<dim3(32, 8), 256, 0, stream>>>(
      ctxb, ctxb, ctxb, Wto, bo, bo, bo, nullptr, nullptr, nullptr,
      (float*)d_out);
}